// Round 2
// baseline (291.658 us; speedup 1.0000x reference)
//
#include <hip/hip_runtime.h>
#include <hip/hip_fp16.h>

#define BG 64
#define NN 2048
#define MM 2048
#define CC 64
#define HH 128
#define NNZE 32768
#define TH 384  // 3*H

typedef float f4v __attribute__((ext_vector_type(4)));  // nt-builtin rejects HIP float4

// ---------------- x (fp32) -> xh (fp16 RNE), packed 2 features per uint ----------------
// XCD-swizzled to match spmm's graph->XCD mapping (graph g on XCD g>>3) and launched
// immediately before spmm. NT reads: the 64 MB x stream must not evict the 32 MB of xh
// this kernel writes (R10 showed zero xh survived with cached reads -> spmm FETCH 52 MB
// = full compulsory; R8 variant with an nt-kept-clean L2 retained ~18 MB).
__global__ __launch_bounds__(256) void cvt_x_kernel(const float* __restrict__ x,
                                                    uint* __restrict__ xh) {
    int bid = blockIdx.x;                       // 8192 blocks, 128 per graph
    int j = bid >> 3;                           // 0..1023
    int g = ((bid & 7) << 3) + (j >> 7);        // XCD = bid&7 = g>>3
    int chunk = j & 127;
    int tid = g * 32768 + chunk * 256 + threadIdx.x;  // group-of-8-floats index
    const f4v* x4 = (const f4v*)x;
    f4v a = __builtin_nontemporal_load(&x4[2 * tid]);
    f4v b = __builtin_nontemporal_load(&x4[2 * tid + 1]);
    __half2 h0 = __float22half2_rn(make_float2(a.x, a.y));
    __half2 h1 = __float22half2_rn(make_float2(a.z, a.w));
    __half2 h2 = __float22half2_rn(make_float2(b.x, b.y));
    __half2 h3 = __float22half2_rn(make_float2(b.z, b.w));
    uint4 o;
    o.x = *(uint*)&h0;
    o.y = *(uint*)&h1;
    o.z = *(uint*)&h2;
    o.w = *(uint*)&h3;
    ((uint4*)xh)[tid] = o;
}

// ---------------- prep phase A: per-(graph, quarter) counting, 256 blocks ----------------
__global__ __launch_bounds__(1024) void prep_count_kernel(const int* __restrict__ d_rows,
                                                          const int* __restrict__ d_index,
                                                          int* __restrict__ cnt_blk,
                                                          int* __restrict__ cnt_clu_blk) {
    __shared__ int cnt_row_s[MM];
    __shared__ int cnt_clu_s[CC];
    int gb = blockIdx.x;  // g*4 + b
    int g = gb >> 2, b = gb & 3;
    int t = threadIdx.x;
    cnt_row_s[t] = 0;
    cnt_row_s[t + 1024] = 0;
    if (t < CC) cnt_clu_s[t] = 0;
    __syncthreads();
    const int* rows_g = d_rows + ((size_t)g << 15) + (b << 13);
#pragma unroll
    for (int it = 0; it < 8; it++) atomicAdd(&cnt_row_s[rows_g[it * 1024 + t]], 1);
    if (t < 512) atomicAdd(&cnt_clu_s[d_index[(g << 11) + (b << 9) + t]], 1);
    __syncthreads();
    int* cb = cnt_blk + (size_t)gb * MM;
    cb[t] = cnt_row_s[t];
    cb[t + 1024] = cnt_row_s[t + 1024];
    if (t < CC) cnt_clu_blk[gb * CC + t] = cnt_clu_s[t];
}

// ---------------- prep phase B: per-graph scans, rlist, per-block base offsets ----------------
__global__ __launch_bounds__(1024) void prep_scan_kernel(const int* __restrict__ d_index,
                                                         const int* __restrict__ cnt_blk,
                                                         const int* __restrict__ cnt_clu_blk,
                                                         int* __restrict__ cnt_clu_g,
                                                         int* __restrict__ off_clu_g,
                                                         int* __restrict__ row_edge_off_g,
                                                         int* __restrict__ off_row_blk,
                                                         int* __restrict__ end_pos) {
    __shared__ int cnt_clu_s[CC], off_clu_s[CC], fill_clu_s[CC];
    __shared__ int rlist_s[MM];
    __shared__ int rowtot_s[MM];
    __shared__ int blk1_s[MM], blk2_s[MM], blk3_s[MM];
    __shared__ int off_row_s[MM];
    __shared__ int wsum[16];
    int g = blockIdx.x, t = threadIdx.x;
    int lane = t & 63, w = t >> 6;

    // row totals + per-block prefixes (coalesced)
    const int* cb = cnt_blk + ((size_t)g << 2) * MM;
    for (int r = t; r < MM; r += 1024) {
        int c0 = cb[r], c1 = cb[MM + r], c2 = cb[2 * MM + r], c3 = cb[3 * MM + r];
        blk1_s[r] = c0;
        blk2_s[r] = c0 + c1;
        blk3_s[r] = c0 + c1 + c2;
        rowtot_s[r] = c0 + c1 + c2 + c3;
    }
    // cluster counts + scan (wave 0)
    if (t < CC) {
        const int* ccb = cnt_clu_blk + (g << 2) * CC;
        int v = ccb[t] + ccb[CC + t] + ccb[2 * CC + t] + ccb[3 * CC + t];
        cnt_clu_s[t] = v;
        fill_clu_s[t] = 0;
        int incl = v;
#pragma unroll
        for (int d = 1; d < 64; d <<= 1) {
            int u = __shfl_up(incl, d);
            if (t >= d) incl += u;
        }
        off_clu_s[t] = incl - v;
        cnt_clu_g[(g << 6) + t] = v;
        off_clu_g[(g << 6) + t] = incl - v;
    }
    int idx0 = d_index[(g << 11) + t];
    int idx1 = d_index[(g << 11) + t + 1024];
    __syncthreads();

    // rlist: rows in cluster-major order
    {
        int s0 = atomicAdd(&fill_clu_s[idx0], 1);
        rlist_s[off_clu_s[idx0] + s0] = t;
        int s1 = atomicAdd(&fill_clu_s[idx1], 1);
        rlist_s[off_clu_s[idx1] + s1] = t + 1024;
    }
    __syncthreads();

    // cluster-major scan of row totals (thread t owns j=2t, 2t+1)
    int r0 = rlist_s[2 * t], r1 = rlist_s[2 * t + 1];
    int c0 = rowtot_s[r0], c1 = rowtot_s[r1];
    int s = c0 + c1;
    int incl = s;
#pragma unroll
    for (int d = 1; d < 64; d <<= 1) {
        int u = __shfl_up(incl, d);
        if (lane >= d) incl += u;
    }
    if (lane == 63) wsum[w] = incl;
    __syncthreads();
    if (t < 16) {
        int v = wsum[t], iv = v;
#pragma unroll
        for (int d = 1; d < 16; d <<= 1) {
            int u = __shfl_up(iv, d);
            if (t >= d) iv += u;
        }
        wsum[t] = iv - v;  // exclusive
    }
    __syncthreads();
    {
        int base = wsum[w] + incl - s;
        int* reo = row_edge_off_g + g * (MM + 1);
        reo[2 * t] = base;
        reo[2 * t + 1] = base + c0;
        off_row_s[r0] = base;
        off_row_s[r1] = base + c0;
        if (t == 0) reo[MM] = NNZE;
    }
    __syncthreads();

    // emit per-(block,row) bases + end positions (coalesced by r)
    int* ob = off_row_blk + ((size_t)g << 2) * MM;
    int* epp = end_pos + (size_t)g * MM;
    for (int r = t; r < MM; r += 1024) {
        int orr = off_row_s[r];
        ob[r] = orr;
        ob[MM + r] = orr + blk1_s[r];
        ob[2 * MM + r] = orr + blk2_s[r];
        ob[3 * MM + r] = orr + blk3_s[r];
        epp[r] = orr + rowtot_s[r];
    }
}

// ---------------- prep phase C: per-(graph, quarter) binning, 256 blocks ----------------
// each block owns pre-reserved sub-ranges -> LDS-only slot allocation; flag is position-based.
// Plain (write-back) stores: nt-hint on scattered 8B stores caused 4x write amplification (R9).
__global__ __launch_bounds__(1024) void prep_bin_kernel(const int* __restrict__ d_rows,
                                                        const int* __restrict__ d_cols,
                                                        const float* __restrict__ d_vals,
                                                        const int* __restrict__ off_row_blk,
                                                        const int* __restrict__ end_pos,
                                                        int2* __restrict__ epack) {
    __shared__ int off_s[MM];
    __shared__ int end_s[MM];
    __shared__ int fill_s[MM];
    int gb = blockIdx.x;
    int g = gb >> 2, b = gb & 3;
    int t = threadIdx.x;
    const int* ob = off_row_blk + (size_t)gb * MM;
    const int* epp = end_pos + (size_t)g * MM;
    off_s[t] = ob[t];
    off_s[t + 1024] = ob[t + 1024];
    end_s[t] = epp[t];
    end_s[t + 1024] = epp[t + 1024];
    fill_s[t] = 0;
    fill_s[t + 1024] = 0;
    __syncthreads();
    const int* rows_g = d_rows + ((size_t)g << 15) + (b << 13);
    const int* cols_g = d_cols + ((size_t)g << 15) + (b << 13);
    const float* vals_g = d_vals + ((size_t)g << 15) + (b << 13);
    int2* epg = epack + ((size_t)g << 15);
#pragma unroll
    for (int it = 0; it < 8; it++) {
        int e = it * 1024 + t;
        int r = rows_g[e];
        int slot = atomicAdd(&fill_s[r], 1);
        int pos = off_s[r] + slot;
        int flag = (pos == end_s[r] - 1) ? (int)0x80000000 : 0;
        epg[pos] = make_int2(cols_g[e] | flag, __float_as_int(vals_g[e]));
    }
}

// ---------------- fused SpMM + mean/max/sum pooling, fp16 x ----------------
// R12: two waves per cluster (128-thr block), R0 inner loop restored verbatim.
// R11 post-mortem: paired-edge gathers regressed (77us, VGPR 28 not 60-120) -- the AMDGPU
// scheduler refuses to keep deep gather batches register-resident regardless of source-level
// batching, so per-wave MLP is pinned at ~3-4 outstanding gathers. The lever that remains is
// WAVE COUNT: R0's grid (4096 one-wave blocks) filled only 16/32 waves per CU (Occupancy 24%),
// and at ~250cy L2 latency the measured 0.22 lines/cy/CU needs exactly the ~56 outstanding
// lines that 16 waves x 3.5 gathers provide -- latency-bound on resident-wave count.
// Wave w of the block takes rows [w*rcnt/2,(w+1)*rcnt/2) (whole rows -> flag/flush logic
// unchanged); partial sum/max combined through 1KB LDS. 4096 blocks x 2 waves = 32 waves/CU.
__global__ __launch_bounds__(128) void spmm_pool_kernel(const uint* __restrict__ xh,
                                                        const int* __restrict__ cnt_clu,
                                                        const int* __restrict__ off_clu,
                                                        const int* __restrict__ row_edge_off,
                                                        const int2* __restrict__ epack,
                                                        float* __restrict__ xdec) {
    __shared__ float2 ssum[64];
    __shared__ float2 smx[64];
    // XCD-aware swizzle: bid&7 -> XCD, graphs [8q, 8q+7] on XCD q (matches cvt_x)
    int bid = blockIdx.x;
    int l = bid >> 3;
    int g = ((bid & 7) << 3) + (l >> 6);
    int c = l & 63;
    int t = threadIdx.x;   // 0..127
    int h = t & 63;        // lane: feature pair 2h, 2h+1
    int w = t >> 6;        // wave 0/1: row-range half
    int gc = (g << 6) + c;
    int rcnt = cnt_clu[gc];
    int j0 = off_clu[gc];
    const int* reo = row_edge_off + g * (MM + 1) + j0;
    int rs = (rcnt * w) >> 1;
    int re = (rcnt * (w + 1)) >> 1;
    int ebase = reo[rs];
    int etot = reo[re] - ebase;
    const long long* ep = (const long long*)(epack + ((size_t)g << 15)) + ebase;
    const uint* xg = xh + ((size_t)g << 17);  // g*N*(H/2) uints
    float2 coef = make_float2(0.f, 0.f), sum = make_float2(0.f, 0.f);
    float2 mx = make_float2(-__builtin_inff(), -__builtin_inff());
    int e = 0;
    for (; e + 16 <= etot; e += 16) {
        long long q[16];
#pragma unroll
        for (int k = 0; k < 16; k++) q[k] = __builtin_nontemporal_load(&ep[e + k]);
        uint xv[16];
#pragma unroll
        for (int k = 0; k < 16; k++)
            xv[k] = xg[(((uint)(int)q[k] & 0x7FFFFFFFu) << 6) + h];
#pragma unroll
        for (int k = 0; k < 16; k++) {
            float v = __int_as_float((int)(q[k] >> 32));
            float2 f = __half22float2(*(__half2*)&xv[k]);
            coef.x = fmaf(v, f.x, coef.x);
            coef.y = fmaf(v, f.y, coef.y);
            if ((int)q[k] < 0) {  // wave-uniform (all lanes see same edge)
                sum.x += coef.x; sum.y += coef.y;
                mx.x = fmaxf(mx.x, coef.x); mx.y = fmaxf(mx.y, coef.y);
                coef.x = 0.f; coef.y = 0.f;
            }
        }
    }
    for (; e < etot; e++) {
        long long q = ep[e];
        uint xv = xg[(((uint)(int)q & 0x7FFFFFFFu) << 6) + h];
        float v = __int_as_float((int)(q >> 32));
        float2 f = __half22float2(*(__half2*)&xv);
        coef.x = fmaf(v, f.x, coef.x);
        coef.y = fmaf(v, f.y, coef.y);
        if ((int)q < 0) {
            sum.x += coef.x; sum.y += coef.y;
            mx.x = fmaxf(mx.x, coef.x); mx.y = fmaxf(mx.y, coef.y);
            coef.x = 0.f; coef.y = 0.f;
        }
    }
    // rows with zero edges in THIS wave's range contribute coef==0 to the max
    int az = 0;
    for (int j = rs + h; j < re; j += 64) az |= (reo[j + 1] == reo[j]);
    if (__ballot(az) != 0ULL) {
        mx.x = fmaxf(mx.x, 0.f);
        mx.y = fmaxf(mx.y, 0.f);
    }
    // combine the two waves' partials (sum is additive over rows, max is max over rows)
    if (w == 1) {
        ssum[h] = sum;
        smx[h] = mx;
    }
    __syncthreads();
    if (w == 0) {
        float2 s1 = ssum[h], m1 = smx[h];
        sum.x += s1.x; sum.y += s1.y;
        mx.x = fmaxf(mx.x, m1.x);
        mx.y = fmaxf(mx.y, m1.y);
        float inv = 1.f / (float)(rcnt > 0 ? rcnt : 1);
        float* xd = xdec + (size_t)gc * TH;
        *(float2*)&xd[2 * h] = make_float2(sum.x * inv, sum.y * inv);
        *(float2*)&xd[HH + 2 * h] = mx;
        *(float2*)&xd[2 * HH + 2 * h] = sum;
    }
}

// ---------------- QKV projection: [4096,384] @ [384,384] -> QKV [4096,384] ----------------
__global__ __launch_bounds__(256) void qkv_kernel(const float* __restrict__ xdec,
                                                  const float* __restrict__ Wq,
                                                  const float* __restrict__ Wk,
                                                  const float* __restrict__ Wv,
                                                  float* __restrict__ QKV) {
    __shared__ float As[16][68];  // A^T tile: [k][row], pad avoids bank conflicts
    __shared__ float Bs[16][64];  // [k][col]
    int bx = blockIdx.x, by = blockIdx.y;
    int t = threadIdx.x;
    int tx = t & 15, ty = t >> 4;
    const float* W = (by < 2) ? Wq : (by < 4) ? Wk : Wv;
    int cbase = (by & 1) * 64;
    int r0 = bx * 64;
    float acc[4][4] = {};
    int lrow = t >> 2, lk4 = (t & 3) * 4;
    for (int k0 = 0; k0 < TH; k0 += 16) {
        float4 av = *(const float4*)&xdec[(size_t)(r0 + lrow) * TH + k0 + lk4];
        As[lk4][lrow] = av.x;
        As[lk4 + 1][lrow] = av.y;
        As[lk4 + 2][lrow] = av.z;
        As[lk4 + 3][lrow] = av.w;
        *(float4*)&Bs[ty][tx * 4] = *(const float4*)&W[(size_t)(k0 + ty) * HH + cbase + tx * 4];
        __syncthreads();
#pragma unroll
        for (int k = 0; k < 16; k++) {
            float4 a = *(float4*)&As[k][ty * 4];
            float4 b = *(float4*)&Bs[k][tx * 4];
            float ar[4] = {a.x, a.y, a.z, a.w};
            float br[4] = {b.x, b.y, b.z, b.w};
#pragma unroll
            for (int i = 0; i < 4; i++)
#pragma unroll
                for (int j = 0; j < 4; j++) acc[i][j] = fmaf(ar[i], br[j], acc[i][j]);
        }
        __syncthreads();
    }
#pragma unroll
    for (int i = 0; i < 4; i++) {
        *(float4*)&QKV[(size_t)(r0 + ty * 4 + i) * TH + by * 64 + tx * 4] =
            make_float4(acc[i][0], acc[i][1], acc[i][2], acc[i][3]);
    }
}

// ---------------- per-graph 64x64 attention ----------------
__global__ __launch_bounds__(256) void attn_kernel(const float* __restrict__ QKV,
                                                   float* __restrict__ out) {
    __shared__ float Qs[16][132];
    __shared__ float sc[16][68];
    int g = blockIdx.x;
    int q0 = blockIdx.y * 16;
    int t = threadIdx.x;
    const float* base = QKV + (size_t)(g * CC) * TH;
    for (int u = t; u < 512; u += 256) {
        int i = u >> 5, cc = u & 31;
        *(float4*)&Qs[i][cc * 4] = *(const float4*)&base[(size_t)(q0 + i) * TH + cc * 4];
    }
    __syncthreads();
    {  // scores: thread (iq, j) computes rows iq, iq+4, iq+8, iq+12 vs col j
        int j = t & 63, iq = t >> 6;
        float a0 = 0, a1 = 0, a2 = 0, a3 = 0;
        const float* Krow = base + (size_t)j * TH + HH;
#pragma unroll 4
        for (int cc = 0; cc < 32; cc++) {
            float4 kv = *(const float4*)&Krow[cc * 4];
            float4 q0v = *(float4*)&Qs[iq][cc * 4];
            float4 q1v = *(float4*)&Qs[4 + iq][cc * 4];
            float4 q2v = *(float4*)&Qs[8 + iq][cc * 4];
            float4 q3v = *(float4*)&Qs[12 + iq][cc * 4];
            a0 += kv.x * q0v.x + kv.y * q0v.y + kv.z * q0v.z + kv.w * q0v.w;
            a1 += kv.x * q1v.x + kv.y * q1v.y + kv.z * q1v.z + kv.w * q1v.w;
            a2 += kv.x * q2v.x + kv.y * q2v.y + kv.z * q2v.z + kv.w * q2v.w;
            a3 += kv.x * q3v.x + kv.y * q3v.y + kv.z * q3v.z + kv.w * q3v.w;
        }
        const float scale = 0.08838834764831845f;  // 1/sqrt(128)
        sc[iq][j] = a0 * scale;
        sc[4 + iq][j] = a1 * scale;
        sc[8 + iq][j] = a2 * scale;
        sc[12 + iq][j] = a3 * scale;
    }
    __syncthreads();
    {  // softmax: 16 threads per row, 4 cols each
        int i = t >> 4, l = t & 15;
        float4 sv = *(float4*)&sc[i][l * 4];
        float m = fmaxf(fmaxf(sv.x, sv.y), fmaxf(sv.z, sv.w));
#pragma unroll
        for (int d = 1; d < 16; d <<= 1) m = fmaxf(m, __shfl_xor(m, d));
        float4 p;
        p.x = __expf(sv.x - m);
        p.y = __expf(sv.y - m);
        p.z = __expf(sv.z - m);
        p.w = __expf(sv.w - m);
        float s = p.x + p.y + p.z + p.w;
#pragma unroll
        for (int d = 1; d < 16; d <<= 1) s += __shfl_xor(s, d);
        float inv = 1.0f / s;
        p.x *= inv; p.y *= inv; p.z *= inv; p.w *= inv;
        *(float4*)&sc[i][l * 4] = p;
    }
    __syncthreads();
    {  // PV: thread (i, hq) computes out[i][hq*8 .. +8)
        int i = t >> 4, hq = t & 15;
        const float* Vbase = base + 2 * HH;
        float acc[8] = {};
        for (int j = 0; j < 64; j++) {
            float d = sc[i][j];
            float4 v0 = *(const float4*)&Vbase[(size_t)j * TH + hq * 8];
            float4 v1 = *(const float4*)&Vbase[(size_t)j * TH + hq * 8 + 4];
            acc[0] = fmaf(d, v0.x, acc[0]);
            acc[1] = fmaf(d, v0.y, acc[1]);
            acc[2] = fmaf(d, v0.z, acc[2]);
            acc[3] = fmaf(d, v0.w, acc[3]);
            acc[4] = fmaf(d, v1.x, acc[4]);
            acc[5] = fmaf(d, v1.y, acc[5]);
            acc[6] = fmaf(d, v1.z, acc[6]);
            acc[7] = fmaf(d, v1.w, acc[7]);
        }
        float* op = out + (size_t)g * (CC * HH) + (size_t)(q0 + i) * HH + hq * 8;
        *(float4*)&op[0] = make_float4(acc[0], acc[1], acc[2], acc[3]);
        *(float4*)&op[4] = make_float4(acc[4], acc[5], acc[6], acc[7]);
    }
}

extern "C" void kernel_launch(void* const* d_in, const int* in_sizes, int n_in,
                              void* d_out, int out_size, void* d_ws, size_t ws_size,
                              hipStream_t stream) {
    const float* x = (const float*)d_in[0];
    // d_in[1] = batch (unused: nodes sorted, equal graph sizes), d_in[2] = batch_size (compile-time 64)
    const int* d_rows = (const int*)d_in[3];
    const int* d_cols = (const int*)d_in[4];
    const float* d_vals = (const float*)d_in[5];
    const int* d_index = (const int*)d_in[6];
    const float* Wq = (const float*)d_in[7];
    const float* Wk = (const float*)d_in[8];
    const float* Wv = (const float*)d_in[9];
    float* out = (float*)d_out;

    char* ws = (char*)d_ws;
    size_t o = 0;
    uint* xh = (uint*)(ws + o); o += (size_t)BG * NN * (HH / 2) * 4;  // 32 MB fp16 x
    int2* epack = (int2*)(ws + o); o += (size_t)BG * NNZE * 8;        // 16 MB
    int* cnt_blk = (int*)(ws + o); o += (size_t)BG * 4 * MM * 4;      // 2 MB
    int* off_row_blk = (int*)(ws + o); o += (size_t)BG * 4 * MM * 4;  // 2 MB
    int* end_pos = (int*)(ws + o); o += (size_t)BG * MM * 4;
    int* cnt_clu_blk = (int*)(ws + o); o += (size_t)BG * 4 * CC * 4;
    int* row_edge_off = (int*)(ws + o); o += (size_t)BG * (MM + 1) * 4;
    int* cnt_clu = (int*)(ws + o); o += (size_t)BG * CC * 4;
    int* off_clu = (int*)(ws + o); o += (size_t)BG * CC * 4;
    float* xdec = (float*)(ws + o); o += (size_t)BG * CC * TH * 4;
    float* QKV = (float*)(ws + o); o += (size_t)BG * CC * TH * 4;

    prep_count_kernel<<<BG * 4, 1024, 0, stream>>>(d_rows, d_index, cnt_blk, cnt_clu_blk);
    prep_scan_kernel<<<BG, 1024, 0, stream>>>(d_index, cnt_blk, cnt_clu_blk,
                                              cnt_clu, off_clu, row_edge_off,
                                              off_row_blk, end_pos);
    prep_bin_kernel<<<BG * 4, 1024, 0, stream>>>(d_rows, d_cols, d_vals,
                                                 off_row_blk, end_pos, epack);
    // cvt_x LAST before spmm: XCD-aligned nt-read/cached-write leaves xh resident in L2
    cvt_x_kernel<<<BG * NN * HH / 8 / 256, 256, 0, stream>>>(x, xh);
    spmm_pool_kernel<<<BG * CC, 128, 0, stream>>>(xh, cnt_clu, off_clu, row_edge_off,
                                                  epack, xdec);
    qkv_kernel<<<dim3(64, 6), 256, 0, stream>>>(xdec, Wq, Wk, Wv, QKV);
    attn_kernel<<<dim3(BG, 4), 256, 0, stream>>>(QKV, out);
}

// Round 4
// 286.671 us; speedup vs baseline: 1.0174x; 1.0174x over previous
//
#include <hip/hip_runtime.h>
#include <hip/hip_fp16.h>

#define BG 64
#define NN 2048
#define MM 2048
#define CC 64
#define HH 128
#define NNZE 32768
#define TH 384  // 3*H

typedef float f4v __attribute__((ext_vector_type(4)));  // nt-builtin rejects HIP float4

// scattered gather into LDS: per-lane GLOBAL src, linear LDS dst (base + lane*16)
#define GLOAD_LDS16(SRC, DST)                                             \
    __builtin_amdgcn_global_load_lds(                                     \
        (const __attribute__((address_space(1))) uint*)(SRC),             \
        (__attribute__((address_space(3))) uint*)(DST), 16, 0, 0)

// ---------------- x (fp32) -> xh (fp16 RNE), packed 2 features per uint ----------------
// XCD-swizzled to match spmm's graph->XCD mapping (graph g on XCD g>>3) and launched
// immediately before spmm. NT reads: the 64 MB x stream must not evict the 32 MB of xh
// this kernel writes.
__global__ __launch_bounds__(256) void cvt_x_kernel(const float* __restrict__ x,
                                                    uint* __restrict__ xh) {
    int bid = blockIdx.x;                       // 8192 blocks, 128 per graph
    int j = bid >> 3;                           // 0..1023
    int g = ((bid & 7) << 3) + (j >> 7);        // XCD = bid&7 = g>>3
    int chunk = j & 127;
    int tid = g * 32768 + chunk * 256 + threadIdx.x;  // group-of-8-floats index
    const f4v* x4 = (const f4v*)x;
    f4v a = __builtin_nontemporal_load(&x4[2 * tid]);
    f4v b = __builtin_nontemporal_load(&x4[2 * tid + 1]);
    __half2 h0 = __float22half2_rn(make_float2(a.x, a.y));
    __half2 h1 = __float22half2_rn(make_float2(a.z, a.w));
    __half2 h2 = __float22half2_rn(make_float2(b.x, b.y));
    __half2 h3 = __float22half2_rn(make_float2(b.z, b.w));
    uint4 o;
    o.x = *(uint*)&h0;
    o.y = *(uint*)&h1;
    o.z = *(uint*)&h2;
    o.w = *(uint*)&h3;
    ((uint4*)xh)[tid] = o;
}

// ---------------- prep phase A: per-(graph, quarter) counting, 256 blocks ----------------
__global__ __launch_bounds__(1024) void prep_count_kernel(const int* __restrict__ d_rows,
                                                          const int* __restrict__ d_index,
                                                          int* __restrict__ cnt_blk,
                                                          int* __restrict__ cnt_clu_blk) {
    __shared__ int cnt_row_s[MM];
    __shared__ int cnt_clu_s[CC];
    int gb = blockIdx.x;  // g*4 + b
    int g = gb >> 2, b = gb & 3;
    int t = threadIdx.x;
    cnt_row_s[t] = 0;
    cnt_row_s[t + 1024] = 0;
    if (t < CC) cnt_clu_s[t] = 0;
    __syncthreads();
    const int* rows_g = d_rows + ((size_t)g << 15) + (b << 13);
#pragma unroll
    for (int it = 0; it < 8; it++) atomicAdd(&cnt_row_s[rows_g[it * 1024 + t]], 1);
    if (t < 512) atomicAdd(&cnt_clu_s[d_index[(g << 11) + (b << 9) + t]], 1);
    __syncthreads();
    int* cb = cnt_blk + (size_t)gb * MM;
    cb[t] = cnt_row_s[t];
    cb[t + 1024] = cnt_row_s[t + 1024];
    if (t < CC) cnt_clu_blk[gb * CC + t] = cnt_clu_s[t];
}

// ---------------- prep phase B: per-graph scans, rlist, per-block base offsets ----------------
__global__ __launch_bounds__(1024) void prep_scan_kernel(const int* __restrict__ d_index,
                                                         const int* __restrict__ cnt_blk,
                                                         const int* __restrict__ cnt_clu_blk,
                                                         int* __restrict__ cnt_clu_g,
                                                         int* __restrict__ off_clu_g,
                                                         int* __restrict__ row_edge_off_g,
                                                         int* __restrict__ off_row_blk,
                                                         int* __restrict__ end_pos) {
    __shared__ int cnt_clu_s[CC], off_clu_s[CC], fill_clu_s[CC];
    __shared__ int rlist_s[MM];
    __shared__ int rowtot_s[MM];
    __shared__ int blk1_s[MM], blk2_s[MM], blk3_s[MM];
    __shared__ int off_row_s[MM];
    __shared__ int wsum[16];
    int g = blockIdx.x, t = threadIdx.x;
    int lane = t & 63, w = t >> 6;

    // row totals + per-block prefixes (coalesced)
    const int* cb = cnt_blk + ((size_t)g << 2) * MM;
    for (int r = t; r < MM; r += 1024) {
        int c0 = cb[r], c1 = cb[MM + r], c2 = cb[2 * MM + r], c3 = cb[3 * MM + r];
        blk1_s[r] = c0;
        blk2_s[r] = c0 + c1;
        blk3_s[r] = c0 + c1 + c2;
        rowtot_s[r] = c0 + c1 + c2 + c3;
    }
    // cluster counts + scan (wave 0)
    if (t < CC) {
        const int* ccb = cnt_clu_blk + (g << 2) * CC;
        int v = ccb[t] + ccb[CC + t] + ccb[2 * CC + t] + ccb[3 * CC + t];
        cnt_clu_s[t] = v;
        fill_clu_s[t] = 0;
        int incl = v;
#pragma unroll
        for (int d = 1; d < 64; d <<= 1) {
            int u = __shfl_up(incl, d);
            if (t >= d) incl += u;
        }
        off_clu_s[t] = incl - v;
        cnt_clu_g[(g << 6) + t] = v;
        off_clu_g[(g << 6) + t] = incl - v;
    }
    int idx0 = d_index[(g << 11) + t];
    int idx1 = d_index[(g << 11) + t + 1024];
    __syncthreads();

    // rlist: rows in cluster-major order
    {
        int s0 = atomicAdd(&fill_clu_s[idx0], 1);
        rlist_s[off_clu_s[idx0] + s0] = t;
        int s1 = atomicAdd(&fill_clu_s[idx1], 1);
        rlist_s[off_clu_s[idx1] + s1] = t + 1024;
    }
    __syncthreads();

    // cluster-major scan of row totals (thread t owns j=2t, 2t+1)
    int r0 = rlist_s[2 * t], r1 = rlist_s[2 * t + 1];
    int c0 = rowtot_s[r0], c1 = rowtot_s[r1];
    int s = c0 + c1;
    int incl = s;
#pragma unroll
    for (int d = 1; d < 64; d <<= 1) {
        int u = __shfl_up(incl, d);
        if (lane >= d) incl += u;
    }
    if (lane == 63) wsum[w] = incl;
    __syncthreads();
    if (t < 16) {
        int v = wsum[t], iv = v;
#pragma unroll
        for (int d = 1; d < 16; d <<= 1) {
            int u = __shfl_up(iv, d);
            if (t >= d) iv += u;
        }
        wsum[t] = iv - v;  // exclusive
    }
    __syncthreads();
    {
        int base = wsum[w] + incl - s;
        int* reo = row_edge_off_g + g * (MM + 1);
        reo[2 * t] = base;
        reo[2 * t + 1] = base + c0;
        off_row_s[r0] = base;
        off_row_s[r1] = base + c0;
        if (t == 0) reo[MM] = NNZE;
    }
    __syncthreads();

    // emit per-(block,row) bases + end positions (coalesced by r)
    int* ob = off_row_blk + ((size_t)g << 2) * MM;
    int* epp = end_pos + (size_t)g * MM;
    for (int r = t; r < MM; r += 1024) {
        int orr = off_row_s[r];
        ob[r] = orr;
        ob[MM + r] = orr + blk1_s[r];
        ob[2 * MM + r] = orr + blk2_s[r];
        ob[3 * MM + r] = orr + blk3_s[r];
        epp[r] = orr + rowtot_s[r];
    }
}

// ---------------- prep phase C: per-(graph, quarter) binning, 256 blocks ----------------
// each block owns pre-reserved sub-ranges -> LDS-only slot allocation; flag is position-based.
__global__ __launch_bounds__(1024) void prep_bin_kernel(const int* __restrict__ d_rows,
                                                        const int* __restrict__ d_cols,
                                                        const float* __restrict__ d_vals,
                                                        const int* __restrict__ off_row_blk,
                                                        const int* __restrict__ end_pos,
                                                        int2* __restrict__ epack) {
    __shared__ int off_s[MM];
    __shared__ int end_s[MM];
    __shared__ int fill_s[MM];
    int gb = blockIdx.x;
    int g = gb >> 2, b = gb & 3;
    int t = threadIdx.x;
    const int* ob = off_row_blk + (size_t)gb * MM;
    const int* epp = end_pos + (size_t)g * MM;
    off_s[t] = ob[t];
    off_s[t + 1024] = ob[t + 1024];
    end_s[t] = epp[t];
    end_s[t + 1024] = epp[t + 1024];
    fill_s[t] = 0;
    fill_s[t + 1024] = 0;
    __syncthreads();
    const int* rows_g = d_rows + ((size_t)g << 15) + (b << 13);
    const int* cols_g = d_cols + ((size_t)g << 15) + (b << 13);
    const float* vals_g = d_vals + ((size_t)g << 15) + (b << 13);
    int2* epg = epack + ((size_t)g << 15);
#pragma unroll
    for (int it = 0; it < 8; it++) {
        int e = it * 1024 + t;
        int r = rows_g[e];
        int slot = atomicAdd(&fill_s[r], 1);
        int pos = off_s[r] + slot;
        int flag = (pos == end_s[r] - 1) ? (int)0x80000000 : 0;
        epg[pos] = make_int2(cols_g[e] | flag, __float_as_int(vals_g[e]));
    }
}

// ---------------- fused SpMM + mean/max/sum pooling, one wave64 per cluster, fp16 x ----------------
// R14 == R13 resubmitted verbatim (R13 bench was an infra failure: container died twice with no
// compile/pytest diagnostic; kernel re-audited for OOB/hang -- all accesses bounds-checked, all
// loops statically bounded, LDS dst wave-uniform+linear per the m104/m108 constraint).
// Theory: gather is bound by the per-CU in-flight-line ceiling (~60-90 64B lines x ~350cy L2
// latency = 17.7 cy/edge at R0). Register-return gathers can't go deeper (allocator sinks
// loads, R11), more waves thrash the shared pool (R12). global_load_lds has NO destination
// VGPR -> in-flight depth is free and un-sinkable. Per-lane GLOBAL src / linear LDS dst
// (lane*16B): one instruction gathers 4 edge rows (1KB, 16 lines); 8 per batch = 128 lines in
// flight per wave (~9x R0). Compute reads rows from LDS (2-way bank = free); q (val|flag)
// broadcast via readlane from one packed per-lane load; batch b+2 addressing prefetched during
// compute of b so the single vmcnt(0) per 32-edge batch waits on gathers that had a full
// compute phase (~400cy) to land. Per-row math order identical to R0 -> bit-identical output.
__global__ __launch_bounds__(64) void spmm_pool_kernel(const uint* __restrict__ xh,
                                                       const int* __restrict__ cnt_clu,
                                                       const int* __restrict__ off_clu,
                                                       const int* __restrict__ row_edge_off,
                                                       const int2* __restrict__ epack,
                                                       float* __restrict__ xdec) {
    __shared__ uint sbuf[2][2048];  // 2 x (32 edges x 256B) = 16 KB
    // XCD-aware swizzle: bid&7 -> XCD, graphs [8q, 8q+7] on XCD q (matches cvt_x)
    int bid = blockIdx.x;
    int l = bid >> 3;
    int g = ((bid & 7) << 3) + (l >> 6);
    int c = l & 63;
    int h = threadIdx.x;  // 0..63
    int sub = h >> 4;     // which of 4 edges in a gather instruction
    int part = h & 15;    // 16B chunk within the 256B row
    int gc = (g << 6) + c;
    int rcnt = cnt_clu[gc];
    int j0 = off_clu[gc];
    const int* reo = row_edge_off + g * (MM + 1) + j0;
    int ebase = reo[0];
    int etot = reo[rcnt] - ebase;
    const long long* ep = (const long long*)(epack + ((size_t)g << 15)) + ebase;
    const uint* xg = xh + ((size_t)g << 17);  // g*N*(H/2) uints; row = 64 uints = 256B
    float2 coef = make_float2(0.f, 0.f), sum = make_float2(0.f, 0.f);
    float2 mx = make_float2(-__builtin_inff(), -__builtin_inff());

#define SPMM_FLUSH                                         \
    do {                                                   \
        sum.x += coef.x; sum.y += coef.y;                  \
        mx.x = fmaxf(mx.x, coef.x);                        \
        mx.y = fmaxf(mx.y, coef.y);                        \
        coef.x = 0.f; coef.y = 0.f;                        \
    } while (0)

    int nb = etot >> 5;  // full 32-edge batches
    long long qC = 0, qA = 0, qB = 0;  // q pack: lanes 2k,2k+1 hold edge k of the batch
    int colA[8], colB[8];
    int cur = 0;

    if (nb > 0) {
        // batch 0 addressing + q
        qC = ep[h >> 1];
        int col0[8];
#pragma unroll
        for (int i = 0; i < 8; i++)
            col0[i] = ((const int*)(ep + 4 * i + sub))[0] & 0x7FFFFFFF;
        asm volatile("s_waitcnt vmcnt(0)" ::: "memory");
#pragma unroll
        for (int i = 0; i < 8; i++)
            GLOAD_LDS16(xg + ((uint)col0[i] << 6) + (part << 2), &sbuf[0][i << 8]);
        if (nb > 1) {  // batch 1 addressing + q (lands during batch-0 compute window)
            const long long* ep1 = ep + 32;
            qA = ep1[h >> 1];
#pragma unroll
            for (int i = 0; i < 8; i++)
                colA[i] = ((const int*)(ep1 + 4 * i + sub))[0] & 0x7FFFFFFF;
        }
    }
    for (int b = 0; b < nb; b++) {
        asm volatile("s_waitcnt vmcnt(0)" ::: "memory");  // gathers b + addr(b+1) landed
        if (b + 1 < nb) {
#pragma unroll
            for (int i = 0; i < 8; i++)
                GLOAD_LDS16(xg + ((uint)colA[i] << 6) + (part << 2),
                            &sbuf[cur ^ 1][i << 8]);
        }
        if (b + 2 < nb) {  // prefetch addressing for b+2; in flight during compute
            const long long* epn = ep + ((b + 2) << 5);
            qB = epn[h >> 1];
#pragma unroll
            for (int i = 0; i < 8; i++)
                colB[i] = ((const int*)(epn + 4 * i + sub))[0] & 0x7FFFFFFF;
        }
        // compute batch b from sbuf[cur]; q values broadcast from qC via readlane
        {
            int qlo = (int)qC, qhi = (int)(qC >> 32);
            const uint* sb = &sbuf[cur][0];
#pragma unroll
            for (int k = 0; k < 32; k++) {
                uint xv = sb[(k << 6) + h];
                int ql = __builtin_amdgcn_readlane(qlo, 2 * k);
                int qh = __builtin_amdgcn_readlane(qhi, 2 * k);
                float v = __int_as_float(qh);
                float2 f = __half22float2(*(__half2*)&xv);
                coef.x = fmaf(v, f.x, coef.x);
                coef.y = fmaf(v, f.y, coef.y);
                if (ql < 0) SPMM_FLUSH;  // wave-uniform scalar branch
            }
        }
        qC = qA;
        qA = qB;
#pragma unroll
        for (int i = 0; i < 8; i++) colA[i] = colB[i];
        cur ^= 1;
    }
    // tail: R0-style per-edge register gather
    for (int e = nb << 5; e < etot; e++) {
        long long q = ep[e];
        uint xv = xg[(((uint)(int)q & 0x7FFFFFFFu) << 6) + h];
        float v = __int_as_float((int)(q >> 32));
        float2 f = __half22float2(*(__half2*)&xv);
        coef.x = fmaf(v, f.x, coef.x);
        coef.y = fmaf(v, f.y, coef.y);
        if ((int)q < 0) SPMM_FLUSH;
    }

    // rows with zero edges contribute coef==0 to the max
    int az = 0;
    for (int j = h; j < rcnt; j += 64) az |= (reo[j + 1] == reo[j]);
    if (__ballot(az) != 0ULL) {
        mx.x = fmaxf(mx.x, 0.f);
        mx.y = fmaxf(mx.y, 0.f);
    }
    float inv = 1.f / (float)(rcnt > 0 ? rcnt : 1);
    float* xd = xdec + (size_t)gc * TH;
    *(float2*)&xd[2 * h] = make_float2(sum.x * inv, sum.y * inv);
    *(float2*)&xd[HH + 2 * h] = mx;
    *(float2*)&xd[2 * HH + 2 * h] = sum;
#undef SPMM_FLUSH
}

// ---------------- QKV projection: [4096,384] @ [384,384] -> QKV [4096,384] ----------------
__global__ __launch_bounds__(256) void qkv_kernel(const float* __restrict__ xdec,
                                                  const float* __restrict__ Wq,
                                                  const float* __restrict__ Wk,
                                                  const float* __restrict__ Wv,
                                                  float* __restrict__ QKV) {
    __shared__ float As[16][68];  // A^T tile: [k][row], pad avoids bank conflicts
    __shared__ float Bs[16][64];  // [k][col]
    int bx = blockIdx.x, by = blockIdx.y;
    int t = threadIdx.x;
    int tx = t & 15, ty = t >> 4;
    const float* W = (by < 2) ? Wq : (by < 4) ? Wk : Wv;
    int cbase = (by & 1) * 64;
    int r0 = bx * 64;
    float acc[4][4] = {};
    int lrow = t >> 2, lk4 = (t & 3) * 4;
    for (int k0 = 0; k0 < TH; k0 += 16) {
        float4 av = *(const float4*)&xdec[(size_t)(r0 + lrow) * TH + k0 + lk4];
        As[lk4][lrow] = av.x;
        As[lk4 + 1][lrow] = av.y;
        As[lk4 + 2][lrow] = av.z;
        As[lk4 + 3][lrow] = av.w;
        *(float4*)&Bs[ty][tx * 4] = *(const float4*)&W[(size_t)(k0 + ty) * HH + cbase + tx * 4];
        __syncthreads();
#pragma unroll
        for (int k = 0; k < 16; k++) {
            float4 a = *(float4*)&As[k][ty * 4];
            float4 b = *(float4*)&Bs[k][tx * 4];
            float ar[4] = {a.x, a.y, a.z, a.w};
            float br[4] = {b.x, b.y, b.z, b.w};
#pragma unroll
            for (int i = 0; i < 4; i++)
#pragma unroll
                for (int j = 0; j < 4; j++) acc[i][j] = fmaf(ar[i], br[j], acc[i][j]);
        }
        __syncthreads();
    }
#pragma unroll
    for (int i = 0; i < 4; i++) {
        *(float4*)&QKV[(size_t)(r0 + ty * 4 + i) * TH + by * 64 + tx * 4] =
            make_float4(acc[i][0], acc[i][1], acc[i][2], acc[i][3]);
    }
}

// ---------------- per-graph 64x64 attention ----------------
__global__ __launch_bounds__(256) void attn_kernel(const float* __restrict__ QKV,
                                                   float* __restrict__ out) {
    __shared__ float Qs[16][132];
    __shared__ float sc[16][68];
    int g = blockIdx.x;
    int q0 = blockIdx.y * 16;
    int t = threadIdx.x;
    const float* base = QKV + (size_t)(g * CC) * TH;
    for (int u = t; u < 512; u += 256) {
        int i = u >> 5, cc = u & 31;
        *(float4*)&Qs[i][cc * 4] = *(const float4*)&base[(size_t)(q0 + i) * TH + cc * 4];
    }
    __syncthreads();
    {  // scores: thread (iq, j) computes rows iq, iq+4, iq+8, iq+12 vs col j
        int j = t & 63, iq = t >> 6;
        float a0 = 0, a1 = 0, a2 = 0, a3 = 0;
        const float* Krow = base + (size_t)j * TH + HH;
#pragma unroll 4
        for (int cc = 0; cc < 32; cc++) {
            float4 kv = *(const float4*)&Krow[cc * 4];
            float4 q0v = *(float4*)&Qs[iq][cc * 4];
            float4 q1v = *(float4*)&Qs[4 + iq][cc * 4];
            float4 q2v = *(float4*)&Qs[8 + iq][cc * 4];
            float4 q3v = *(float4*)&Qs[12 + iq][cc * 4];
            a0 += kv.x * q0v.x + kv.y * q0v.y + kv.z * q0v.z + kv.w * q0v.w;
            a1 += kv.x * q1v.x + kv.y * q1v.y + kv.z * q1v.z + kv.w * q1v.w;
            a2 += kv.x * q2v.x + kv.y * q2v.y + kv.z * q2v.z + kv.w * q2v.w;
            a3 += kv.x * q3v.x + kv.y * q3v.y + kv.z * q3v.z + kv.w * q3v.w;
        }
        const float scale = 0.08838834764831845f;  // 1/sqrt(128)
        sc[iq][j] = a0 * scale;
        sc[4 + iq][j] = a1 * scale;
        sc[8 + iq][j] = a2 * scale;
        sc[12 + iq][j] = a3 * scale;
    }
    __syncthreads();
    {  // softmax: 16 threads per row, 4 cols each
        int i = t >> 4, l = t & 15;
        float4 sv = *(float4*)&sc[i][l * 4];
        float m = fmaxf(fmaxf(sv.x, sv.y), fmaxf(sv.z, sv.w));
#pragma unroll
        for (int d = 1; d < 16; d <<= 1) m = fmaxf(m, __shfl_xor(m, d));
        float4 p;
        p.x = __expf(sv.x - m);
        p.y = __expf(sv.y - m);
        p.z = __expf(sv.z - m);
        p.w = __expf(sv.w - m);
        float s = p.x + p.y + p.z + p.w;
#pragma unroll
        for (int d = 1; d < 16; d <<= 1) s += __shfl_xor(s, d);
        float inv = 1.0f / s;
        p.x *= inv; p.y *= inv; p.z *= inv; p.w *= inv;
        *(float4*)&sc[i][l * 4] = p;
    }
    __syncthreads();
    {  // PV: thread (i, hq) computes out[i][hq*8 .. +8)
        int i = t >> 4, hq = t & 15;
        const float* Vbase = base + 2 * HH;
        float acc[8] = {};
        for (int j = 0; j < 64; j++) {
            float d = sc[i][j];
            float4 v0 = *(const float4*)&Vbase[(size_t)j * TH + hq * 8];
            float4 v1 = *(const float4*)&Vbase[(size_t)j * TH + hq * 8 + 4];
            acc[0] = fmaf(d, v0.x, acc[0]);
            acc[1] = fmaf(d, v0.y, acc[1]);
            acc[2] = fmaf(d, v0.z, acc[2]);
            acc[3] = fmaf(d, v0.w, acc[3]);
            acc[4] = fmaf(d, v1.x, acc[4]);
            acc[5] = fmaf(d, v1.y, acc[5]);
            acc[6] = fmaf(d, v1.z, acc[6]);
            acc[7] = fmaf(d, v1.w, acc[7]);
        }
        float* op = out + (size_t)g * (CC * HH) + (size_t)(q0 + i) * HH + hq * 8;
        *(float4*)&op[0] = make_float4(acc[0], acc[1], acc[2], acc[3]);
        *(float4*)&op[4] = make_float4(acc[4], acc[5], acc[6], acc[7]);
    }
}

extern "C" void kernel_launch(void* const* d_in, const int* in_sizes, int n_in,
                              void* d_out, int out_size, void* d_ws, size_t ws_size,
                              hipStream_t stream) {
    const float* x = (const float*)d_in[0];
    // d_in[1] = batch (unused: nodes sorted, equal graph sizes), d_in[2] = batch_size (compile-time 64)
    const int* d_rows = (const int*)d_in[3];
    const int* d_cols = (const int*)d_in[4];
    const float* d_vals = (const float*)d_in[5];
    const int* d_index = (const int*)d_in[6];
    const float* Wq = (const float*)d_in[7];
    const float* Wk = (const float*)d_in[8];
    const float* Wv = (const float*)d_in[9];
    float* out = (float*)d_out;

    char* ws = (char*)d_ws;
    size_t o = 0;
    uint* xh = (uint*)(ws + o); o += (size_t)BG * NN * (HH / 2) * 4;  // 32 MB fp16 x
    int2* epack = (int2*)(ws + o); o += (size_t)BG * NNZE * 8;        // 16 MB
    int* cnt_blk = (int*)(ws + o); o += (size_t)BG * 4 * MM * 4;      // 2 MB
    int* off_row_blk = (int*)(ws + o); o += (size_t)BG * 4 * MM * 4;  // 2 MB
    int* end_pos = (int*)(ws + o); o += (size_t)BG * MM * 4;
    int* cnt_clu_blk = (int*)(ws + o); o += (size_t)BG * 4 * CC * 4;
    int* row_edge_off = (int*)(ws + o); o += (size_t)BG * (MM + 1) * 4;
    int* cnt_clu = (int*)(ws + o); o += (size_t)BG * CC * 4;
    int* off_clu = (int*)(ws + o); o += (size_t)BG * CC * 4;
    float* xdec = (float*)(ws + o); o += (size_t)BG * CC * TH * 4;
    float* QKV = (float*)(ws + o); o += (size_t)BG * CC * TH * 4;

    prep_count_kernel<<<BG * 4, 1024, 0, stream>>>(d_rows, d_index, cnt_blk, cnt_clu_blk);
    prep_scan_kernel<<<BG, 1024, 0, stream>>>(d_index, cnt_blk, cnt_clu_blk,
                                              cnt_clu, off_clu, row_edge_off,
                                              off_row_blk, end_pos);
    prep_bin_kernel<<<BG * 4, 1024, 0, stream>>>(d_rows, d_cols, d_vals,
                                                 off_row_blk, end_pos, epack);
    // cvt_x LAST before spmm: XCD-aligned nt-read/cached-write leaves xh resident in L2
    cvt_x_kernel<<<BG * NN * HH / 8 / 256, 256, 0, stream>>>(x, xh);
    spmm_pool_kernel<<<BG * CC, 64, 0, stream>>>(xh, cnt_clu, off_clu, row_edge_off,
                                                 epack, xdec);
    qkv_kernel<<<dim3(64, 6), 256, 0, stream>>>(xdec, Wq, Wk, Wv, QKV);
    attn_kernel<<<dim3(BG, 4), 256, 0, stream>>>(QKV, out);
}

// Round 5
// 257.997 us; speedup vs baseline: 1.1305x; 1.1111x over previous
//
#include <hip/hip_runtime.h>
#include <hip/hip_fp16.h>

#define BG 64
#define NN 2048
#define MM 2048
#define CC 64
#define HH 128
#define NNZE 32768
#define TH 384  // 3*H

typedef float f4v __attribute__((ext_vector_type(4)));  // nt-builtin rejects HIP float4
typedef __attribute__((ext_vector_type(8))) short bf16x8;
typedef __attribute__((ext_vector_type(4))) float f32x4;
typedef unsigned short u16;

// RNE f32 -> bf16 (no NaN in data paths here)
static __device__ __forceinline__ u16 bf16rne(float f) {
    uint u = __float_as_uint(f);
    uint r = u + 0x7FFFu + ((u >> 16) & 1u);
    return (u16)(r >> 16);
}
static __device__ __forceinline__ float bf16tof(u16 h) {
    return __uint_as_float(((uint)h) << 16);
}

// ---------------- prep phase A + fused x->fp16 conversion + fused W bf16-split ----------------
// R15: cvt_x fused here. R10 evidence: zero xh survives L2 into spmm regardless of ordering
// (spmm FETCH 52 MB = full compulsory), so "cvt last before spmm" bought nothing; fusing hides
// cvt's 96 MB stream under the LDS-atomic counting phase and removes a launch. Also splits
// Wq/Wk/Wv into transposed bf16 hi/lo pairs ([3][128 n][384 k]) for the MFMA qkv.
__global__ __launch_bounds__(1024) void prep_count_kernel(const int* __restrict__ d_rows,
                                                          const int* __restrict__ d_index,
                                                          const float* __restrict__ x,
                                                          const float* __restrict__ Wq,
                                                          const float* __restrict__ Wk,
                                                          const float* __restrict__ Wv,
                                                          int* __restrict__ cnt_blk,
                                                          int* __restrict__ cnt_clu_blk,
                                                          uint* __restrict__ xh,
                                                          u16* __restrict__ WhT,
                                                          u16* __restrict__ WlT) {
    __shared__ int cnt_row_s[MM];
    __shared__ int cnt_clu_s[CC];
    int gb = blockIdx.x;  // g*4 + b
    int g = gb >> 2, b = gb & 3;
    int t = threadIdx.x;
    cnt_row_s[t] = 0;
    cnt_row_s[t + 1024] = 0;
    if (t < CC) cnt_clu_s[t] = 0;
    __syncthreads();
    const int* rows_g = d_rows + ((size_t)g << 15) + (b << 13);
#pragma unroll
    for (int it = 0; it < 8; it++) atomicAdd(&cnt_row_s[rows_g[it * 1024 + t]], 1);
    if (t < 512) atomicAdd(&cnt_clu_s[d_index[(g << 11) + (b << 9) + t]], 1);

    // fused x (fp32) -> xh (fp16 RNE, 2 feats/uint): same work split as old cvt_x
    {
        const f4v* x4 = (const f4v*)x;
        uint4* xh4 = (uint4*)xh;
#pragma unroll
        for (int it = 0; it < 8; it++) {
            int tidg = (gb << 13) + it * 1024 + t;  // 8-float group index
            f4v a = __builtin_nontemporal_load(&x4[2 * tidg]);
            f4v bb = __builtin_nontemporal_load(&x4[2 * tidg + 1]);
            __half2 h0 = __float22half2_rn(make_float2(a.x, a.y));
            __half2 h1 = __float22half2_rn(make_float2(a.z, a.w));
            __half2 h2 = __float22half2_rn(make_float2(bb.x, bb.y));
            __half2 h3 = __float22half2_rn(make_float2(bb.z, bb.w));
            uint4 o;
            o.x = *(uint*)&h0;
            o.y = *(uint*)&h1;
            o.z = *(uint*)&h2;
            o.w = *(uint*)&h3;
            xh4[tidg] = o;
        }
    }
    // fused W split+transpose: 3*384*128 = 147456 elems over blocks 0..143
    if (gb < 144) {
        int id = (gb << 10) + t;
        int w = id / 49152;
        int r = id - w * 49152;          // r = k*128 + n
        const float* Ws = (w == 0) ? Wq : (w == 1) ? Wk : Wv;
        float v = Ws[r];
        int k = r >> 7, n = r & 127;
        u16 hi = bf16rne(v);
        u16 lo = bf16rne(v - bf16tof(hi));
        WhT[w * 49152 + n * 384 + k] = hi;
        WlT[w * 49152 + n * 384 + k] = lo;
    }
    __syncthreads();
    int* cb = cnt_blk + (size_t)gb * MM;
    cb[t] = cnt_row_s[t];
    cb[t + 1024] = cnt_row_s[t + 1024];
    if (t < CC) cnt_clu_blk[gb * CC + t] = cnt_clu_s[t];
}

// ---------------- prep phase B: per-graph scans, rlist, per-block base offsets ----------------
__global__ __launch_bounds__(1024) void prep_scan_kernel(const int* __restrict__ d_index,
                                                         const int* __restrict__ cnt_blk,
                                                         const int* __restrict__ cnt_clu_blk,
                                                         int* __restrict__ cnt_clu_g,
                                                         int* __restrict__ off_clu_g,
                                                         int* __restrict__ row_edge_off_g,
                                                         int* __restrict__ off_row_blk,
                                                         int* __restrict__ end_pos) {
    __shared__ int cnt_clu_s[CC], off_clu_s[CC], fill_clu_s[CC];
    __shared__ int rlist_s[MM];
    __shared__ int rowtot_s[MM];
    __shared__ int blk1_s[MM], blk2_s[MM], blk3_s[MM];
    __shared__ int off_row_s[MM];
    __shared__ int wsum[16];
    int g = blockIdx.x, t = threadIdx.x;
    int lane = t & 63, w = t >> 6;

    // row totals + per-block prefixes (coalesced)
    const int* cb = cnt_blk + ((size_t)g << 2) * MM;
    for (int r = t; r < MM; r += 1024) {
        int c0 = cb[r], c1 = cb[MM + r], c2 = cb[2 * MM + r], c3 = cb[3 * MM + r];
        blk1_s[r] = c0;
        blk2_s[r] = c0 + c1;
        blk3_s[r] = c0 + c1 + c2;
        rowtot_s[r] = c0 + c1 + c2 + c3;
    }
    // cluster counts + scan (wave 0)
    if (t < CC) {
        const int* ccb = cnt_clu_blk + (g << 2) * CC;
        int v = ccb[t] + ccb[CC + t] + ccb[2 * CC + t] + ccb[3 * CC + t];
        cnt_clu_s[t] = v;
        fill_clu_s[t] = 0;
        int incl = v;
#pragma unroll
        for (int d = 1; d < 64; d <<= 1) {
            int u = __shfl_up(incl, d);
            if (t >= d) incl += u;
        }
        off_clu_s[t] = incl - v;
        cnt_clu_g[(g << 6) + t] = v;
        off_clu_g[(g << 6) + t] = incl - v;
    }
    int idx0 = d_index[(g << 11) + t];
    int idx1 = d_index[(g << 11) + t + 1024];
    __syncthreads();

    // rlist: rows in cluster-major order
    {
        int s0 = atomicAdd(&fill_clu_s[idx0], 1);
        rlist_s[off_clu_s[idx0] + s0] = t;
        int s1 = atomicAdd(&fill_clu_s[idx1], 1);
        rlist_s[off_clu_s[idx1] + s1] = t + 1024;
    }
    __syncthreads();

    // cluster-major scan of row totals (thread t owns j=2t, 2t+1)
    int r0 = rlist_s[2 * t], r1 = rlist_s[2 * t + 1];
    int c0 = rowtot_s[r0], c1 = rowtot_s[r1];
    int s = c0 + c1;
    int incl = s;
#pragma unroll
    for (int d = 1; d < 64; d <<= 1) {
        int u = __shfl_up(incl, d);
        if (lane >= d) incl += u;
    }
    if (lane == 63) wsum[w] = incl;
    __syncthreads();
    if (t < 16) {
        int v = wsum[t], iv = v;
#pragma unroll
        for (int d = 1; d < 16; d <<= 1) {
            int u = __shfl_up(iv, d);
            if (t >= d) iv += u;
        }
        wsum[t] = iv - v;  // exclusive
    }
    __syncthreads();
    {
        int base = wsum[w] + incl - s;
        int* reo = row_edge_off_g + g * (MM + 1);
        reo[2 * t] = base;
        reo[2 * t + 1] = base + c0;
        off_row_s[r0] = base;
        off_row_s[r1] = base + c0;
        if (t == 0) reo[MM] = NNZE;
    }
    __syncthreads();

    // emit per-(block,row) bases + end positions (coalesced by r)
    int* ob = off_row_blk + ((size_t)g << 2) * MM;
    int* epp = end_pos + (size_t)g * MM;
    for (int r = t; r < MM; r += 1024) {
        int orr = off_row_s[r];
        ob[r] = orr;
        ob[MM + r] = orr + blk1_s[r];
        ob[2 * MM + r] = orr + blk2_s[r];
        ob[3 * MM + r] = orr + blk3_s[r];
        epp[r] = orr + rowtot_s[r];
    }
}

// ---------------- prep phase C: per-(graph, quarter) binning, 256 blocks ----------------
// each block owns pre-reserved sub-ranges -> LDS-only slot allocation; flag is position-based.
__global__ __launch_bounds__(1024) void prep_bin_kernel(const int* __restrict__ d_rows,
                                                        const int* __restrict__ d_cols,
                                                        const float* __restrict__ d_vals,
                                                        const int* __restrict__ off_row_blk,
                                                        const int* __restrict__ end_pos,
                                                        int2* __restrict__ epack) {
    __shared__ int off_s[MM];
    __shared__ int end_s[MM];
    __shared__ int fill_s[MM];
    int gb = blockIdx.x;
    int g = gb >> 2, b = gb & 3;
    int t = threadIdx.x;
    const int* ob = off_row_blk + (size_t)gb * MM;
    const int* epp = end_pos + (size_t)g * MM;
    off_s[t] = ob[t];
    off_s[t + 1024] = ob[t + 1024];
    end_s[t] = epp[t];
    end_s[t + 1024] = epp[t + 1024];
    fill_s[t] = 0;
    fill_s[t + 1024] = 0;
    __syncthreads();
    const int* rows_g = d_rows + ((size_t)g << 15) + (b << 13);
    const int* cols_g = d_cols + ((size_t)g << 15) + (b << 13);
    const float* vals_g = d_vals + ((size_t)g << 15) + (b << 13);
    int2* epg = epack + ((size_t)g << 15);
#pragma unroll
    for (int it = 0; it < 8; it++) {
        int e = it * 1024 + t;
        int r = rows_g[e];
        int slot = atomicAdd(&fill_s[r], 1);
        int pos = off_s[r] + slot;
        int flag = (pos == end_s[r] - 1) ? (int)0x80000000 : 0;
        epg[pos] = make_int2(cols_g[e] | flag, __float_as_int(vals_g[e]));
    }
}

// ---------------- fused SpMM + mean/max/sum pooling, one wave64 per cluster, fp16 x ----------------
// R15: inner loop reverted to R0 EXACTLY (60.6us, the best of 4 structures; R11/R12/R14 all
// regressed -> per-CU scattered-line rate ~4.4cy/line is the HW ceiling, R0 already sits on it).
// Epilogue change only: write xdec as split-bf16 (hi + lo = fp32-accurate pair) for MFMA qkv.
__global__ __launch_bounds__(64) void spmm_pool_kernel(const uint* __restrict__ xh,
                                                       const int* __restrict__ cnt_clu,
                                                       const int* __restrict__ off_clu,
                                                       const int* __restrict__ row_edge_off,
                                                       const int2* __restrict__ epack,
                                                       u16* __restrict__ xdh,
                                                       u16* __restrict__ xdl) {
    // XCD-aware swizzle: bid&7 -> XCD, graphs [8q, 8q+7] on XCD q
    int bid = blockIdx.x;
    int l = bid >> 3;
    int g = ((bid & 7) << 3) + (l >> 6);
    int c = l & 63;
    int h = threadIdx.x;  // 0..63
    int gc = (g << 6) + c;
    int rcnt = cnt_clu[gc];
    int j0 = off_clu[gc];
    const int* reo = row_edge_off + g * (MM + 1) + j0;
    int ebase = reo[0];
    int etot = reo[rcnt] - ebase;
    const long long* ep = (const long long*)(epack + ((size_t)g << 15)) + ebase;
    const uint* xg = xh + ((size_t)g << 17);  // g*N*(H/2) uints
    float2 coef = make_float2(0.f, 0.f), sum = make_float2(0.f, 0.f);
    float2 mx = make_float2(-__builtin_inff(), -__builtin_inff());
    int e = 0;
    for (; e + 16 <= etot; e += 16) {
        long long q[16];
#pragma unroll
        for (int k = 0; k < 16; k++) q[k] = __builtin_nontemporal_load(&ep[e + k]);
        uint xv[16];
#pragma unroll
        for (int k = 0; k < 16; k++)
            xv[k] = xg[(((uint)(int)q[k] & 0x7FFFFFFFu) << 6) + h];
#pragma unroll
        for (int k = 0; k < 16; k++) {
            float v = __int_as_float((int)(q[k] >> 32));
            float2 f = __half22float2(*(__half2*)&xv[k]);
            coef.x = fmaf(v, f.x, coef.x);
            coef.y = fmaf(v, f.y, coef.y);
            if ((int)q[k] < 0) {  // wave-uniform (all lanes see same edge)
                sum.x += coef.x; sum.y += coef.y;
                mx.x = fmaxf(mx.x, coef.x); mx.y = fmaxf(mx.y, coef.y);
                coef.x = 0.f; coef.y = 0.f;
            }
        }
    }
    for (; e < etot; e++) {
        long long q = ep[e];
        uint xv = xg[(((uint)(int)q & 0x7FFFFFFFu) << 6) + h];
        float v = __int_as_float((int)(q >> 32));
        float2 f = __half22float2(*(__half2*)&xv);
        coef.x = fmaf(v, f.x, coef.x);
        coef.y = fmaf(v, f.y, coef.y);
        if ((int)q < 0) {
            sum.x += coef.x; sum.y += coef.y;
            mx.x = fmaxf(mx.x, coef.x); mx.y = fmaxf(mx.y, coef.y);
            coef.x = 0.f; coef.y = 0.f;
        }
    }
    // rows with zero edges contribute coef==0 to the max
    int az = 0;
    for (int j = h; j < rcnt; j += 64) az |= (reo[j + 1] == reo[j]);
    if (__ballot(az) != 0ULL) {
        mx.x = fmaxf(mx.x, 0.f);
        mx.y = fmaxf(mx.y, 0.f);
    }
    float inv = 1.f / (float)(rcnt > 0 ? rcnt : 1);
    // split-bf16 epilogue: lane h owns feature pair (2h, 2h+1) of each of mean|max|sum
    uint* oh = (uint*)xdh + (size_t)gc * 192 + h;
    uint* ol = (uint*)xdl + (size_t)gc * 192 + h;
    float me0 = sum.x * inv, me1 = sum.y * inv;
    u16 a0 = bf16rne(me0), a1 = bf16rne(me1);
    oh[0] = (uint)a0 | ((uint)a1 << 16);
    ol[0] = (uint)bf16rne(me0 - bf16tof(a0)) | ((uint)bf16rne(me1 - bf16tof(a1)) << 16);
    u16 b0 = bf16rne(mx.x), b1 = bf16rne(mx.y);
    oh[64] = (uint)b0 | ((uint)b1 << 16);
    ol[64] = (uint)bf16rne(mx.x - bf16tof(b0)) | ((uint)bf16rne(mx.y - bf16tof(b1)) << 16);
    u16 c0 = bf16rne(sum.x), c1 = bf16rne(sum.y);
    oh[128] = (uint)c0 | ((uint)c1 << 16);
    ol[128] = (uint)bf16rne(sum.x - bf16tof(c0)) | ((uint)bf16rne(sum.y - bf16tof(c1)) << 16);
}

// ---------------- QKV projection via split-bf16 triple-MFMA ----------------
// R15: fp32 vector GEMM has a hard 23us floor (3.62 GFLOP / 157 TF); this was the invisible
// #2 consumer (~30us). Split x = hi + lo (bf16 RNE + residual): A.B ~= Ah.Bh + Ah.Bl + Al.Bh,
// rel err ~2^-16 ~ fp32 -> accuracy unchanged, runs on the 2.5 PF matrix pipe.
// Fragment layouts (guide m89/m91 + HK swapped-QK derivation): A: m=lane&15, k=8*(lane>>4)+e
// contiguous; B: n=lane&15, same k (B staged as W^T [n][k]); D: n=lane&15, m=4*(lane>>4)+r.
// LDS rows padded to 40 u16 (80B stride): 16B-aligned b128, uniform 2-way banks (free).
__global__ __launch_bounds__(256) void qkv_kernel(const u16* __restrict__ xdh,
                                                  const u16* __restrict__ xdl,
                                                  const u16* __restrict__ WhT,
                                                  const u16* __restrict__ WlT,
                                                  float* __restrict__ QKV) {
    __shared__ u16 Ah[64][40], Al[64][40], Bh[64][40], Bl[64][40];
    int bx = blockIdx.x, by = blockIdx.y;
    int t = threadIdx.x;
    int w = by >> 1;
    int cb = (by & 1) << 6;     // col base within this W
    int r0 = bx << 6;
    const u16* wh = WhT + w * 49152;
    const u16* wl = WlT + w * 49152;
    int lane = t & 63, wv = t >> 6;
    int wm = wv >> 1, wn = wv & 1;          // wave -> 32x32 quadrant
    int srow = t >> 2, sks = (t & 3) << 3;  // staging: row, k-chunk (8 elems)
    int fr = lane & 15, fk = (lane >> 4) << 3;  // fragment row/col + k base
    f32x4 acc[2][2];
#pragma unroll
    for (int i = 0; i < 2; i++)
#pragma unroll
        for (int j = 0; j < 2; j++)
#pragma unroll
            for (int r = 0; r < 4; r++) acc[i][j][r] = 0.f;
    for (int ks = 0; ks < 12; ks++) {
        int k0 = ks << 5;
        bf16x8 sa_h = *(const bf16x8*)&xdh[(size_t)(r0 + srow) * 384 + k0 + sks];
        bf16x8 sa_l = *(const bf16x8*)&xdl[(size_t)(r0 + srow) * 384 + k0 + sks];
        bf16x8 sb_h = *(const bf16x8*)&wh[(size_t)(cb + srow) * 384 + k0 + sks];
        bf16x8 sb_l = *(const bf16x8*)&wl[(size_t)(cb + srow) * 384 + k0 + sks];
        if (ks) __syncthreads();  // previous iteration's fragment reads must finish
        *(bf16x8*)&Ah[srow][sks] = sa_h;
        *(bf16x8*)&Al[srow][sks] = sa_l;
        *(bf16x8*)&Bh[srow][sks] = sb_h;
        *(bf16x8*)&Bl[srow][sks] = sb_l;
        __syncthreads();
        bf16x8 fa_h[2], fa_l[2], fb_h[2], fb_l[2];
#pragma unroll
        for (int mi = 0; mi < 2; mi++) {
            int ar = (wm << 5) + (mi << 4) + fr;
            fa_h[mi] = *(const bf16x8*)&Ah[ar][fk];
            fa_l[mi] = *(const bf16x8*)&Al[ar][fk];
        }
#pragma unroll
        for (int ni = 0; ni < 2; ni++) {
            int br = (wn << 5) + (ni << 4) + fr;
            fb_h[ni] = *(const bf16x8*)&Bh[br][fk];
            fb_l[ni] = *(const bf16x8*)&Bl[br][fk];
        }
#pragma unroll
        for (int mi = 0; mi < 2; mi++)
#pragma unroll
            for (int ni = 0; ni < 2; ni++) {
                acc[mi][ni] = __builtin_amdgcn_mfma_f32_16x16x32_bf16(
                    fa_h[mi], fb_h[ni], acc[mi][ni], 0, 0, 0);
                acc[mi][ni] = __builtin_amdgcn_mfma_f32_16x16x32_bf16(
                    fa_h[mi], fb_l[ni], acc[mi][ni], 0, 0, 0);
                acc[mi][ni] = __builtin_amdgcn_mfma_f32_16x16x32_bf16(
                    fa_l[mi], fb_h[ni], acc[mi][ni], 0, 0, 0);
            }
    }
#pragma unroll
    for (int mi = 0; mi < 2; mi++)
#pragma unroll
        for (int ni = 0; ni < 2; ni++)
#pragma unroll
            for (int r = 0; r < 4; r++) {
                int row = r0 + (wm << 5) + (mi << 4) + ((lane >> 4) << 2) + r;
                int col = (by << 6) + (wn << 5) + (ni << 4) + (lane & 15);
                QKV[(size_t)row * TH + col] = acc[mi][ni][r];
            }
}

// ---------------- per-graph 64x64 attention ----------------
__global__ __launch_bounds__(256) void attn_kernel(const float* __restrict__ QKV,
                                                   float* __restrict__ out) {
    __shared__ float Qs[16][132];
    __shared__ float sc[16][68];
    int g = blockIdx.x;
    int q0 = blockIdx.y * 16;
    int t = threadIdx.x;
    const float* base = QKV + (size_t)(g * CC) * TH;
    for (int u = t; u < 512; u += 256) {
        int i = u >> 5, cc = u & 31;
        *(float4*)&Qs[i][cc * 4] = *(const float4*)&base[(size_t)(q0 + i) * TH + cc * 4];
    }
    __syncthreads();
    {  // scores: thread (iq, j) computes rows iq, iq+4, iq+8, iq+12 vs col j
        int j = t & 63, iq = t >> 6;
        float a0 = 0, a1 = 0, a2 = 0, a3 = 0;
        const float* Krow = base + (size_t)j * TH + HH;
#pragma unroll 4
        for (int cc = 0; cc < 32; cc++) {
            float4 kv = *(const float4*)&Krow[cc * 4];
            float4 q0v = *(float4*)&Qs[iq][cc * 4];
            float4 q1v = *(float4*)&Qs[4 + iq][cc * 4];
            float4 q2v = *(float4*)&Qs[8 + iq][cc * 4];
            float4 q3v = *(float4*)&Qs[12 + iq][cc * 4];
            a0 += kv.x * q0v.x + kv.y * q0v.y + kv.z * q0v.z + kv.w * q0v.w;
            a1 += kv.x * q1v.x + kv.y * q1v.y + kv.z * q1v.z + kv.w * q1v.w;
            a2 += kv.x * q2v.x + kv.y * q2v.y + kv.z * q2v.z + kv.w * q2v.w;
            a3 += kv.x * q3v.x + kv.y * q3v.y + kv.z * q3v.z + kv.w * q3v.w;
        }
        const float scale = 0.08838834764831845f;  // 1/sqrt(128)
        sc[iq][j] = a0 * scale;
        sc[4 + iq][j] = a1 * scale;
        sc[8 + iq][j] = a2 * scale;
        sc[12 + iq][j] = a3 * scale;
    }
    __syncthreads();
    {  // softmax: 16 threads per row, 4 cols each
        int i = t >> 4, l = t & 15;
        float4 sv = *(float4*)&sc[i][l * 4];
        float m = fmaxf(fmaxf(sv.x, sv.y), fmaxf(sv.z, sv.w));
#pragma unroll
        for (int d = 1; d < 16; d <<= 1) m = fmaxf(m, __shfl_xor(m, d));
        float4 p;
        p.x = __expf(sv.x - m);
        p.y = __expf(sv.y - m);
        p.z = __expf(sv.z - m);
        p.w = __expf(sv.w - m);
        float s = p.x + p.y + p.z + p.w;
#pragma unroll
        for (int d = 1; d < 16; d <<= 1) s += __shfl_xor(s, d);
        float inv = 1.0f / s;
        p.x *= inv; p.y *= inv; p.z *= inv; p.w *= inv;
        *(float4*)&sc[i][l * 4] = p;
    }
    __syncthreads();
    {  // PV: thread (i, hq) computes out[i][hq*8 .. +8)
        int i = t >> 4, hq = t & 15;
        const float* Vbase = base + 2 * HH;
        float acc[8] = {};
        for (int j = 0; j < 64; j++) {
            float d = sc[i][j];
            float4 v0 = *(const float4*)&Vbase[(size_t)j * TH + hq * 8];
            float4 v1 = *(const float4*)&Vbase[(size_t)j * TH + hq * 8 + 4];
            acc[0] = fmaf(d, v0.x, acc[0]);
            acc[1] = fmaf(d, v0.y, acc[1]);
            acc[2] = fmaf(d, v0.z, acc[2]);
            acc[3] = fmaf(d, v0.w, acc[3]);
            acc[4] = fmaf(d, v1.x, acc[4]);
            acc[5] = fmaf(d, v1.y, acc[5]);
            acc[6] = fmaf(d, v1.z, acc[6]);
            acc[7] = fmaf(d, v1.w, acc[7]);
        }
        float* op = out + (size_t)g * (CC * HH) + (size_t)(q0 + i) * HH + hq * 8;
        *(float4*)&op[0] = make_float4(acc[0], acc[1], acc[2], acc[3]);
        *(float4*)&op[4] = make_float4(acc[4], acc[5], acc[6], acc[7]);
    }
}

extern "C" void kernel_launch(void* const* d_in, const int* in_sizes, int n_in,
                              void* d_out, int out_size, void* d_ws, size_t ws_size,
                              hipStream_t stream) {
    const float* x = (const float*)d_in[0];
    // d_in[1] = batch (unused: nodes sorted, equal graph sizes), d_in[2] = batch_size (compile-time 64)
    const int* d_rows = (const int*)d_in[3];
    const int* d_cols = (const int*)d_in[4];
    const float* d_vals = (const float*)d_in[5];
    const int* d_index = (const int*)d_in[6];
    const float* Wq = (const float*)d_in[7];
    const float* Wk = (const float*)d_in[8];
    const float* Wv = (const float*)d_in[9];
    float* out = (float*)d_out;

    char* ws = (char*)d_ws;
    size_t o = 0;
    uint* xh = (uint*)(ws + o); o += (size_t)BG * NN * (HH / 2) * 4;  // 32 MB fp16 x
    int2* epack = (int2*)(ws + o); o += (size_t)BG * NNZE * 8;        // 16 MB
    int* cnt_blk = (int*)(ws + o); o += (size_t)BG * 4 * MM * 4;      // 2 MB
    int* off_row_blk = (int*)(ws + o); o += (size_t)BG * 4 * MM * 4;  // 2 MB
    int* end_pos = (int*)(ws + o); o += (size_t)BG * MM * 4;
    int* cnt_clu_blk = (int*)(ws + o); o += (size_t)BG * 4 * CC * 4;
    int* row_edge_off = (int*)(ws + o); o += (size_t)BG * (MM + 1) * 4;
    int* cnt_clu = (int*)(ws + o); o += (size_t)BG * CC * 4;
    int* off_clu = (int*)(ws + o); o += (size_t)BG * CC * 4;
    u16* xdh = (u16*)(ws + o); o += (size_t)BG * CC * TH * 2;   // 3 MB split-bf16 hi
    u16* xdl = (u16*)(ws + o); o += (size_t)BG * CC * TH * 2;   // 3 MB split-bf16 lo
    u16* WhT = (u16*)(ws + o); o += (size_t)3 * HH * TH * 2;    // 288 KB W^T hi
    u16* WlT = (u16*)(ws + o); o += (size_t)3 * HH * TH * 2;    // 288 KB W^T lo
    float* QKV = (float*)(ws + o); o += (size_t)BG * CC * TH * 4;

    prep_count_kernel<<<BG * 4, 1024, 0, stream>>>(d_rows, d_index, x, Wq, Wk, Wv,
                                                   cnt_blk, cnt_clu_blk, xh, WhT, WlT);
    prep_scan_kernel<<<BG, 1024, 0, stream>>>(d_index, cnt_blk, cnt_clu_blk,
                                              cnt_clu, off_clu, row_edge_off,
                                              off_row_blk, end_pos);
    prep_bin_kernel<<<BG * 4, 1024, 0, stream>>>(d_rows, d_cols, d_vals,
                                                 off_row_blk, end_pos, epack);
    spmm_pool_kernel<<<BG * CC, 64, 0, stream>>>(xh, cnt_clu, off_clu, row_edge_off,
                                                 epack, xdh, xdl);
    qkv_kernel<<<dim3(64, 6), 256, 0, stream>>>(xdh, xdl, WhT, WlT, QKV);
    attn_kernel<<<dim3(BG, 4), 256, 0, stream>>>(QKV, out);
}